// Round 1
// baseline (553.276 us; speedup 1.0000x reference)
//
#include <hip/hip_runtime.h>

typedef float floatx4 __attribute__((ext_vector_type(4)));

#define WG 256

// ---------------------------------------------------------------------------
// Detect whether edge_index arrived as int32 or int64.
// For int64 data (all values in [0, N), N < 2^31) every odd 32-bit word is 0.
// For int32 data the odd words are random node ids — virtually surely nonzero.
__global__ __launch_bounds__(WG) void k_detect(const int* __restrict__ w, int* __restrict__ is32) {
    __shared__ int any;
    if (threadIdx.x == 0) any = 0;
    __syncthreads();
    int nz = 0;
    for (int i = threadIdx.x; i < 4096; i += WG) nz |= (w[2 * i + 1] != 0);
    if (nz) any = 1;
    __syncthreads();
    if (threadIdx.x == 0) *is32 = any;
}

// deg[i] = 1 accounts for the self-loop.
__global__ __launch_bounds__(WG) void k_init_deg(int* __restrict__ deg, int N) {
    int i = blockIdx.x * WG + threadIdx.x;
    if (i < N) deg[i] = 1;
}

__global__ __launch_bounds__(WG) void k_count(const void* __restrict__ ei, const int* __restrict__ is32,
                                              int* __restrict__ deg, int E) {
    int e = blockIdx.x * WG + threadIdx.x;
    if (e >= E) return;
    int d = (*is32) ? ((const int*)ei)[E + e]
                    : (int)((const long long*)ei)[(long long)E + e];
    atomicAdd(&deg[d], 1);
}

__global__ __launch_bounds__(WG) void k_dinv(const int* __restrict__ deg, float* __restrict__ dinv, int N) {
    int i = blockIdx.x * WG + threadIdx.x;
    if (i < N) dinv[i] = rsqrtf((float)deg[i]);  // deg >= 1 always (self-loop)
}

__global__ __launch_bounds__(WG) void k_blocksum(const int* __restrict__ deg, int* __restrict__ bs, int N) {
    __shared__ int sm[WG];
    int i = blockIdx.x * WG + threadIdx.x;
    sm[threadIdx.x] = (i < N) ? deg[i] : 0;
    __syncthreads();
    for (int d = WG / 2; d > 0; d >>= 1) {
        if (threadIdx.x < d) sm[threadIdx.x] += sm[threadIdx.x + d];
        __syncthreads();
    }
    if (threadIdx.x == 0) bs[blockIdx.x] = sm[0];
}

// Exclusive scan of per-block sums. NB <= 512 for this problem (N=100000 -> 391).
__global__ __launch_bounds__(512) void k_scanbs(int* __restrict__ bs, int NB) {
    __shared__ int sm[512];
    int t = threadIdx.x;
    int v = (t < NB) ? bs[t] : 0;
    sm[t] = v;
    __syncthreads();
    for (int d = 1; d < 512; d <<= 1) {
        int a = (t >= d) ? sm[t - d] : 0;
        __syncthreads();
        sm[t] += a;
        __syncthreads();
    }
    if (t < NB) bs[t] = sm[t] - v;  // exclusive
}

// off[i] = global exclusive prefix of deg. Pre-fill slot off[i] with the
// self-loop (src = i); cursor starts at off[i]+1 for the real edges.
__global__ __launch_bounds__(WG) void k_makeoff(const int* __restrict__ deg, const int* __restrict__ bs,
                                                int* __restrict__ off, int* __restrict__ cursor,
                                                int* __restrict__ srcs, int N, int total) {
    __shared__ int sm[WG];
    int t = threadIdx.x;
    int i = blockIdx.x * WG + t;
    int v = (i < N) ? deg[i] : 0;
    sm[t] = v;
    __syncthreads();
    for (int d = 1; d < WG; d <<= 1) {
        int a = (t >= d) ? sm[t - d] : 0;
        __syncthreads();
        sm[t] += a;
        __syncthreads();
    }
    if (i < N) {
        int o = bs[blockIdx.x] + sm[t] - v;
        off[i] = o;
        cursor[i] = o + 1;
        srcs[o] = i;  // self-loop entry
    }
    if (i == 0) off[N] = total;
}

__global__ __launch_bounds__(WG) void k_fill(const void* __restrict__ ei, const int* __restrict__ is32,
                                             int* __restrict__ cursor, int* __restrict__ srcs, int E) {
    int e = blockIdx.x * WG + threadIdx.x;
    if (e >= E) return;
    int s, d;
    if (*is32) {
        const int* p = (const int*)ei;
        s = p[e];
        d = p[E + e];
    } else {
        const long long* p = (const long long*)ei;
        s = (int)p[e];
        d = (int)p[(long long)E + e];
    }
    int pos = atomicAdd(&cursor[d], 1);
    srcs[pos] = s;
}

// g[i,:] = dinv[i] * (x[i,:] @ W).  W (256x64, 64 KB) staged in LDS.
// Thread t: cols [8*(t&7), +8), rows rowbase + 4*(t>>3) .. +4.  Block = 128 rows.
// Inner loop: 8 ds_read_b128 reused across 4 rows -> 16 FMA per LDS b128 (VALU-bound).
__global__ __launch_bounds__(WG) void k_gemm(const float* __restrict__ x, const float* __restrict__ W,
                                             const float* __restrict__ dinv, float* __restrict__ g, int N) {
    __shared__ float Ws[256 * 64];  // 64 KB exactly
    {
        const floatx4* W4 = (const floatx4*)W;
        floatx4* S4 = (floatx4*)Ws;
        for (int i = threadIdx.x; i < 4096; i += WG) S4[i] = W4[i];
    }
    __syncthreads();

    const int cg = (threadIdx.x & 7) * 8;
    const int rg = threadIdx.x >> 3;
    const long long rowbase = (long long)blockIdx.x * 128 + (long long)rg * 4;

    floatx4 acc[4][2];
#pragma unroll
    for (int r = 0; r < 4; r++) {
        acc[r][0] = 0.f;
        acc[r][1] = 0.f;
    }

    long long rr[4];
#pragma unroll
    for (int r = 0; r < 4; r++) {
        long long row = rowbase + r;
        rr[r] = (row < N) ? row : (long long)(N - 1);  // clamp; store is guarded
    }

    for (int k = 0; k < 256; k += 4) {
        floatx4 xv[4];
#pragma unroll
        for (int r = 0; r < 4; r++) xv[r] = *(const floatx4*)(x + rr[r] * 256 + k);
#pragma unroll
        for (int kk = 0; kk < 4; kk++) {
            floatx4 wa = *(const floatx4*)(Ws + (k + kk) * 64 + cg);
            floatx4 wb = *(const floatx4*)(Ws + (k + kk) * 64 + cg + 4);
#pragma unroll
            for (int r = 0; r < 4; r++) {
                float xk = xv[r][kk];
                acc[r][0] += wa * xk;
                acc[r][1] += wb * xk;
            }
        }
    }

#pragma unroll
    for (int r = 0; r < 4; r++) {
        long long row = rowbase + r;
        if (row < N) {
            float s = dinv[row];
            *(floatx4*)(g + row * 64 + cg) = acc[r][0] * s;
            *(floatx4*)(g + row * 64 + cg + 4) = acc[r][1] * s;
        }
    }
}

// One wave per destination node; lane = output column (HID = 64 = wavefront).
// Each edge is one coalesced 256 B row read of g (L2/L3-resident).
__global__ __launch_bounds__(WG) void k_gather(const float* __restrict__ g, const int* __restrict__ off,
                                               const int* __restrict__ srcs, const float* __restrict__ dinv,
                                               const float* __restrict__ bias, float* __restrict__ out, int N) {
    int wid = (blockIdx.x * WG + threadIdx.x) >> 6;
    int lane = threadIdx.x & 63;
    if (wid >= N) return;
    int e0 = off[wid], e1 = off[wid + 1];
    float acc = 0.f;
    for (int e = e0; e < e1; ++e) {
        int s = srcs[e];
        acc += g[(long long)s * 64 + lane];
    }
    out[(long long)wid * 64 + lane] = dinv[wid] * acc + bias[lane];
}

extern "C" void kernel_launch(void* const* d_in, const int* in_sizes, int n_in,
                              void* d_out, int out_size, void* d_ws, size_t ws_size,
                              hipStream_t stream) {
    const float* x = (const float*)d_in[0];
    const void* ei = d_in[1];
    const float* W = (const float*)d_in[2];
    const float* b = (const float*)d_in[3];
    float* out = (float*)d_out;

    const int N = in_sizes[0] / 256;
    const int E = in_sizes[1] / 2;
    const int NB = (N + WG - 1) / WG;  // 391 for N=100000 (must be <= 512)
    const int EB = (E + WG - 1) / WG;

    // Workspace carve-up (256 B aligned chunks), total ~34 MB.
    char* ws = (char*)d_ws;
    size_t o = 0;
    auto alloc = [&](size_t bytes) -> void* {
        void* p = ws + o;
        o += (bytes + 255) & ~(size_t)255;
        return p;
    };
    float* dinv = (float*)alloc((size_t)N * 4);
    float* g = (float*)alloc((size_t)N * 64 * 4);
    int* deg = (int*)alloc((size_t)N * 4);
    int* off = (int*)alloc((size_t)(N + 1) * 4);
    int* cursor = (int*)alloc((size_t)N * 4);
    int* srcs = (int*)alloc((size_t)(E + N) * 4);
    int* bs = (int*)alloc(4096);
    int* is32 = (int*)alloc(256);
    if (o > ws_size) return;  // workspace too small: fail visibly rather than corrupt

    k_detect<<<1, WG, 0, stream>>>((const int*)ei, is32);
    k_init_deg<<<NB, WG, 0, stream>>>(deg, N);
    k_count<<<EB, WG, 0, stream>>>(ei, is32, deg, E);
    k_dinv<<<NB, WG, 0, stream>>>(deg, dinv, N);
    k_blocksum<<<NB, WG, 0, stream>>>(deg, bs, N);
    k_scanbs<<<1, 512, 0, stream>>>(bs, NB);
    k_makeoff<<<NB, WG, 0, stream>>>(deg, bs, off, cursor, srcs, N, E + N);
    k_fill<<<EB, WG, 0, stream>>>(ei, is32, cursor, srcs, E);
    k_gemm<<<(N + 127) / 128, WG, 0, stream>>>(x, W, dinv, g, N);
    k_gather<<<(N * 64 + WG - 1) / WG, WG, 0, stream>>>(g, off, srcs, dinv, b, out, N);
}

// Round 2
// 492.764 us; speedup vs baseline: 1.1228x; 1.1228x over previous
//
#include <hip/hip_runtime.h>

typedef float floatx4 __attribute__((ext_vector_type(4)));

#define WG 256

__device__ inline unsigned pack_bf16_rne(float a, float b) {
    unsigned ua = __float_as_uint(a), ub = __float_as_uint(b);
    ua = (ua + 0x7FFFu + ((ua >> 16) & 1u)) >> 16;
    ub = (ub + 0x7FFFu + ((ub >> 16) & 1u)) >> 16;
    return ua | (ub << 16);
}

// ---------------------------------------------------------------------------
// deg[i] = 1 (self-loop); block 0 additionally detects int32 vs int64 edges.
// For int64 data (values < 2^31) every odd 32-bit word is 0; for int32 the
// odd words are random node ids — virtually surely nonzero.
__global__ __launch_bounds__(WG) void k_detect_init(const int* __restrict__ w, int* __restrict__ is32,
                                                    int* __restrict__ deg, int N) {
    int i = blockIdx.x * WG + threadIdx.x;
    if (i < N) deg[i] = 1;
    if (blockIdx.x == 0) {
        __shared__ int any;
        if (threadIdx.x == 0) any = 0;
        __syncthreads();
        int nz = 0;
        for (int j = threadIdx.x; j < 4096; j += WG) nz |= (w[2 * j + 1] != 0);
        if (nz) any = 1;
        __syncthreads();
        if (threadIdx.x == 0) *is32 = any;
    }
}

__global__ __launch_bounds__(WG) void k_count(const void* __restrict__ ei, const int* __restrict__ is32,
                                              int* __restrict__ deg, int E) {
    int e = blockIdx.x * WG + threadIdx.x;
    if (e >= E) return;
    int d = (*is32) ? ((const int*)ei)[E + e]
                    : (int)((const long long*)ei)[(long long)E + e];
    atomicAdd(&deg[d], 1);
}

// dinv[i] = deg^{-1/2}; also per-block sums of deg for the scan.
__global__ __launch_bounds__(WG) void k_dinv_bs(const int* __restrict__ deg, float* __restrict__ dinv,
                                                int* __restrict__ bs, int N) {
    __shared__ int sm[WG];
    int i = blockIdx.x * WG + threadIdx.x;
    int d = (i < N) ? deg[i] : 0;
    if (i < N) dinv[i] = rsqrtf((float)d);  // deg >= 1 always (self-loop)
    sm[threadIdx.x] = d;
    __syncthreads();
    for (int s = WG / 2; s > 0; s >>= 1) {
        if (threadIdx.x < s) sm[threadIdx.x] += sm[threadIdx.x + s];
        __syncthreads();
    }
    if (threadIdx.x == 0) bs[blockIdx.x] = sm[0];
}

// Exclusive scan of per-block sums. NB <= 512 (N=100000 -> 391).
__global__ __launch_bounds__(512) void k_scanbs(int* __restrict__ bs, int NB) {
    __shared__ int sm[512];
    int t = threadIdx.x;
    int v = (t < NB) ? bs[t] : 0;
    sm[t] = v;
    __syncthreads();
    for (int d = 1; d < 512; d <<= 1) {
        int a = (t >= d) ? sm[t - d] : 0;
        __syncthreads();
        sm[t] += a;
        __syncthreads();
    }
    if (t < NB) bs[t] = sm[t] - v;  // exclusive
}

// off[i] = global exclusive prefix of deg. Slot off[i] pre-filled with the
// self-loop (src = i); cursor starts at off[i]+1 for the real edges.
__global__ __launch_bounds__(WG) void k_makeoff(const int* __restrict__ deg, const int* __restrict__ bs,
                                                int* __restrict__ off, int* __restrict__ cursor,
                                                int* __restrict__ srcs, int N, int total) {
    __shared__ int sm[WG];
    int t = threadIdx.x;
    int i = blockIdx.x * WG + t;
    int v = (i < N) ? deg[i] : 0;
    sm[t] = v;
    __syncthreads();
    for (int d = 1; d < WG; d <<= 1) {
        int a = (t >= d) ? sm[t - d] : 0;
        __syncthreads();
        sm[t] += a;
        __syncthreads();
    }
    if (i < N) {
        int o = bs[blockIdx.x] + sm[t] - v;
        off[i] = o;
        cursor[i] = o + 1;
        srcs[o] = i;  // self-loop entry
    }
    if (i == 0) off[N] = total;
}

__global__ __launch_bounds__(WG) void k_fill(const void* __restrict__ ei, const int* __restrict__ is32,
                                             int* __restrict__ cursor, int* __restrict__ srcs, int E) {
    int e = blockIdx.x * WG + threadIdx.x;
    if (e >= E) return;
    int s, d;
    if (*is32) {
        const int* p = (const int*)ei;
        s = p[e];
        d = p[E + e];
    } else {
        const long long* p = (const long long*)ei;
        s = (int)p[e];
        d = (int)p[(long long)E + e];
    }
    int pos = atomicAdd(&cursor[d], 1);
    srcs[pos] = s;
}

// g[i,:] = bf16( dinv[i] * (x[i,:] @ W) ).  W staged in LDS in two 32 KB
// K-halves (128x64 fp32) so LDS caps occupancy at 5 blocks/CU, not 2.
// Thread t: cols [8*(t&7), +8), rows rowbase + 4*(t>>3) .. +4.  Block = 128 rows.
__global__ __launch_bounds__(WG) void k_gemm(const float* __restrict__ x, const float* __restrict__ W,
                                             const float* __restrict__ dinv, unsigned short* __restrict__ g,
                                             int N) {
    __shared__ float Ws[128 * 64];  // 32 KB

    const int cg = (threadIdx.x & 7) * 8;
    const int rg = threadIdx.x >> 3;
    const long long rowbase = (long long)blockIdx.x * 128 + (long long)rg * 4;

    floatx4 acc[4][2];
#pragma unroll
    for (int r = 0; r < 4; r++) {
        acc[r][0] = 0.f;
        acc[r][1] = 0.f;
    }

    long long rr[4];
#pragma unroll
    for (int r = 0; r < 4; r++) {
        long long row = rowbase + r;
        rr[r] = (row < N) ? row : (long long)(N - 1);  // clamp; store is guarded
    }

    for (int half = 0; half < 2; half++) {
        const int kbase = half * 128;
        __syncthreads();  // protect prior half's reads before overwrite
        {
            const floatx4* W4 = (const floatx4*)W + half * 2048;
            floatx4* S4 = (floatx4*)Ws;
            for (int i = threadIdx.x; i < 2048; i += WG) S4[i] = W4[i];
        }
        __syncthreads();

        for (int k = 0; k < 128; k += 4) {
            floatx4 xv[4];
#pragma unroll
            for (int r = 0; r < 4; r++) xv[r] = *(const floatx4*)(x + rr[r] * 256 + kbase + k);
#pragma unroll
            for (int kk = 0; kk < 4; kk++) {
                floatx4 wa = *(const floatx4*)(Ws + (k + kk) * 64 + cg);
                floatx4 wb = *(const floatx4*)(Ws + (k + kk) * 64 + cg + 4);
#pragma unroll
                for (int r = 0; r < 4; r++) {
                    float xk = xv[r][kk];
                    acc[r][0] += wa * xk;
                    acc[r][1] += wb * xk;
                }
            }
        }
    }

#pragma unroll
    for (int r = 0; r < 4; r++) {
        long long row = rowbase + r;
        if (row < N) {
            float s = dinv[row];
            unsigned p0 = pack_bf16_rne(acc[r][0][0] * s, acc[r][0][1] * s);
            unsigned p1 = pack_bf16_rne(acc[r][0][2] * s, acc[r][0][3] * s);
            unsigned p2 = pack_bf16_rne(acc[r][1][0] * s, acc[r][1][1] * s);
            unsigned p3 = pack_bf16_rne(acc[r][1][2] * s, acc[r][1][3] * s);
            uint4 pk = {p0, p1, p2, p3};
            *(uint4*)(g + row * 64 + cg) = pk;  // byte offset cg*2, 16B aligned
        }
    }
}

// One wave per destination node. Wave split into two 32-lane halves; half h
// processes edges e0+h, e0+h+2, ... Each lane loads one bf16x2 (4 B) — a
// half-wave covers the full 128 B row, perfectly coalesced. Halves combined
// via shfl_xor(32) at the end. 2x the outstanding row-loads per wave vs R1.
__global__ __launch_bounds__(WG) void k_gather(const unsigned short* __restrict__ g,
                                               const int* __restrict__ off, const int* __restrict__ srcs,
                                               const float* __restrict__ dinv, const float* __restrict__ bias,
                                               float* __restrict__ out, int N) {
    int wid = (blockIdx.x * WG + threadIdx.x) >> 6;
    int lane = threadIdx.x & 63;
    if (wid >= N) return;
    int h = lane >> 5;
    int c2 = lane & 31;  // column pair: cols 2*c2, 2*c2+1
    int e0 = off[wid], e1 = off[wid + 1];
    float ax = 0.f, ay = 0.f;
    for (int e = e0 + h; e < e1; e += 2) {
        int s = srcs[e];
        unsigned v = *(const unsigned*)(g + (long long)s * 64 + c2 * 2);
        ax += __uint_as_float(v << 16);           // even col (low bf16)
        ay += __uint_as_float(v & 0xFFFF0000u);   // odd col (high bf16)
    }
    ax += __shfl_xor(ax, 32, 64);
    ay += __shfl_xor(ay, 32, 64);
    if (h == 0) {
        float d = dinv[wid];
        float2 o;
        o.x = d * ax + bias[c2 * 2];
        o.y = d * ay + bias[c2 * 2 + 1];
        *(float2*)(out + (long long)wid * 64 + c2 * 2) = o;
    }
}

extern "C" void kernel_launch(void* const* d_in, const int* in_sizes, int n_in,
                              void* d_out, int out_size, void* d_ws, size_t ws_size,
                              hipStream_t stream) {
    const float* x = (const float*)d_in[0];
    const void* ei = d_in[1];
    const float* W = (const float*)d_in[2];
    const float* b = (const float*)d_in[3];
    float* out = (float*)d_out;

    const int N = in_sizes[0] / 256;
    const int E = in_sizes[1] / 2;
    const int NB = (N + WG - 1) / WG;  // 391 for N=100000 (must be <= 512)
    const int EB = (E + WG - 1) / WG;

    char* ws = (char*)d_ws;
    size_t o = 0;
    auto alloc = [&](size_t bytes) -> void* {
        void* p = ws + o;
        o += (bytes + 255) & ~(size_t)255;
        return p;
    };
    float* dinv = (float*)alloc((size_t)N * 4);
    unsigned short* g = (unsigned short*)alloc((size_t)N * 64 * 2);  // bf16
    int* deg = (int*)alloc((size_t)N * 4);
    int* off = (int*)alloc((size_t)(N + 1) * 4);
    int* cursor = (int*)alloc((size_t)N * 4);
    int* srcs = (int*)alloc((size_t)(E + N) * 4);
    int* bs = (int*)alloc(4096);
    int* is32 = (int*)alloc(256);
    if (o > ws_size) return;  // workspace too small: fail visibly rather than corrupt

    k_detect_init<<<NB, WG, 0, stream>>>((const int*)ei, is32, deg, N);
    k_count<<<EB, WG, 0, stream>>>(ei, is32, deg, E);
    k_dinv_bs<<<NB, WG, 0, stream>>>(deg, dinv, bs, N);
    k_scanbs<<<1, 512, 0, stream>>>(bs, NB);
    k_makeoff<<<NB, WG, 0, stream>>>(deg, bs, off, cursor, srcs, N, E + N);
    k_fill<<<EB, WG, 0, stream>>>(ei, is32, cursor, srcs, E);
    k_gemm<<<(N + 127) / 128, WG, 0, stream>>>(x, W, dinv, g, N);
    k_gather<<<(N * 64 + WG - 1) / WG, WG, 0, stream>>>(g, off, srcs, dinv, b, out, N);
}